// Round 5
// baseline (393.276 us; speedup 1.0000x reference)
//
#include <hip/hip_runtime.h>
#include <hip/hip_bf16.h>

// DreamAttention on MI355X.
// Math: out = (Q K^T/sqrt(HD)) V Wo^T  (reference discards softmax!)
//     = Q @ NT_b^T  where NT_b[j][h*128+d1] = sum_d2 (K^T V/sqrt(HD))_bh[d1][d2] * Wo[j][h*128+d2]
// B=2, S=2048, D=2048, NH=16, HD=128.
// Round 5: 8-phase (4 sub-phases per BK=64 K-tile) counted-vmcnt schedule
// (m201/T3+T4+T5), on top of round-4's measured-zero-conflict LDS swizzle.

typedef __attribute__((ext_vector_type(8))) short bf16x8s;   // 8 bf16 in 4 VGPRs
typedef __attribute__((ext_vector_type(4))) float f32x4;

__device__ __forceinline__ ushort f2bf(float f) {
    union { float f; unsigned int u; } x; x.f = f;
    unsigned int u = x.u;
    unsigned int r = (u + 0x7fffu + ((u >> 16) & 1u)) >> 16;   // RTN
    return (ushort)r;
}
__device__ __forceinline__ float b2f(ushort u) {
    union { unsigned int u; float f; } x; x.u = ((unsigned int)u) << 16;
    return x.f;
}

__device__ __forceinline__ void gload_lds16(const void* g, void* l) {
    __builtin_amdgcn_global_load_lds((__attribute__((address_space(1))) const void*)g,
                                     (__attribute__((address_space(3))) void*)l, 16, 0, 0);
}

// ---------------------------------------------------------------------------
// 256x256 NT GEMM, BK=64, 512 thr (8 waves 2Mx4N), 8-phase counted-vmcnt.
// C[m][n] = sum_k A[m][k]*B[n][k] (+bias[n]); bf16 in, fp32 acc.
//
// LDS 128KB: buf b (b=tile&1) at b*65536; A-tile at +0, B-tile at +32768.
// Each tile = 2 16KB blocks (kc=0 at +0, kc=1 at +16384). Each 16KB block
// holds 256 rows x 32 cols bf16 in round-4's proven layout: physical row
// pr = r>>1 (128B), chunk pos = (((r&1)<<2)|j) ^ (pr&7), j = 16B chunk of
// the row's 64B. Frag ds_read_b128 = 2 lanes/bank (measured 0 conflicts);
// staging dst is lane-linear (chunk = tid + s*512), src inverse-permuted.
//
// K-tile t (buf lb), 4 phases, each: [ds_read frags][stage 1 half of t+1
// into lb^64K][barrier][lgkmcnt(0)][16 MFMA, setprio]{vmcnt(4) at ph1,ph3}
// [barrier].  Reads/wave/tile = 8+4+8+4 = 24 (each frag read once).
// vmcnt ledger: in flight after each ph1/ph3 wait = exactly 2 halves
// (4 loads); waits retire precisely the halves the next 2 phases read.
// ---------------------------------------------------------------------------
template<bool BIAS, bool OBF16>
__global__ __launch_bounds__(512, 2)
void gemm256(const ushort* __restrict__ A, const ushort* __restrict__ B,
             const float* __restrict__ bias, void* __restrict__ Cv,
             int K, int lda, int ldb, int ldc,
             long sAb, long sBb, long sCb)
{
    __shared__ char smem[131072];

    int z = blockIdx.z;
    const ushort* Ab = A + (size_t)sAb * z;
    const ushort* Bb = B + (size_t)sBb * z;
    size_t Coff = (size_t)sCb * z;

    // XCD-aware bijective workgroup swizzle (nwg % 8 == 0 for all our grids)
    int nwgx = gridDim.x;
    int nwg = nwgx * gridDim.y;
    int wg = blockIdx.y * nwgx + blockIdx.x;
    int swz = ((nwg & 7) == 0) ? (wg & 7) * (nwg >> 3) + (wg >> 3) : wg;
    int m0 = (swz % nwgx) * 256;
    int n0 = (swz / nwgx) * 256;

    int tid = threadIdx.x;
    int l = tid & 63, wid = tid >> 6;
    int wm = (wid >> 2) * 128;     // wave row half: 0 or 128
    int wn = (wid & 3) * 64;       // wave col quarter: 0/64/128/192
    int lr = l & 15, lj = l >> 4;  // frag: row-within-16, 16B k-chunk

    // fragment LDS byte offsets within a 16KB (kc) block
    int offA[8], offB[4];
#pragma unroll
    for (int m = 0; m < 8; m++) {
        int r = wm + m * 16 + lr;
        offA[m] = (r >> 1) * 128 + (((((r & 1) << 2) | lj) ^ ((r >> 1) & 7)) << 4);
    }
#pragma unroll
    for (int n = 0; n < 4; n++) {
        int r = wn + n * 16 + lr;
        offB[n] = (r >> 1) * 128 + (((((r & 1) << 2) | lj) ^ ((r >> 1) & 7)) << 4);
    }

    // staging: 2 chunks/thread per 16KB half-stage; dst lane-linear,
    // src from the inverse swizzle map (round-4 proven).
    unsigned srcA0, srcA1, srcB0, srcB1;
    int dst0 = tid * 16, dst1 = dst0 + 8192;
    {
        int c0 = tid, c1 = tid + 512;
        int pr0 = c0 >> 3, up0 = (c0 & 7) ^ (pr0 & 7);
        int r0 = (pr0 << 1) | (up0 >> 2), j0 = up0 & 3;
        int pr1 = c1 >> 3, up1 = (c1 & 7) ^ (pr1 & 7);
        int r1 = (pr1 << 1) | (up1 >> 2), j1 = up1 & 3;
        srcA0 = (unsigned)(m0 + r0) * lda + j0 * 8;
        srcA1 = (unsigned)(m0 + r1) * lda + j1 * 8;
        srcB0 = (unsigned)(n0 + r0) * ldb + j0 * 8;
        srcB1 = (unsigned)(n0 + r1) * ldb + j1 * 8;
    }

    f32x4 acc[8][4];
#pragma unroll
    for (int m = 0; m < 8; m++)
#pragma unroll
        for (int n = 0; n < 4; n++)
            acc[m][n] = (f32x4){0.f, 0.f, 0.f, 0.f};

    int NT = K >> 6;   // K-tiles of 64 (K % 64 == 0, NT >= 2)

#define STAGE_A(ldsbyte, eoff) { \
    gload_lds16(Ab + srcA0 + (eoff), smem + (ldsbyte) + dst0); \
    gload_lds16(Ab + srcA1 + (eoff), smem + (ldsbyte) + dst1); }
#define STAGE_B(ldsbyte, eoff) { \
    gload_lds16(Bb + srcB0 + (eoff), smem + (ldsbyte) + dst0); \
    gload_lds16(Bb + srcB1 + (eoff), smem + (ldsbyte) + dst1); }
#define LDA_FRAGS(mb, kadd) { \
    _Pragma("unroll") \
    for (int m = 0; m < 4; m++) \
        af[m] = *(const bf16x8s*)(smem + lb + offA[(mb) + m] + (kadd)); }
#define LDB_FRAGS(kadd) { \
    _Pragma("unroll") \
    for (int n = 0; n < 4; n++) \
        bf[n] = *(const bf16x8s*)(smem + lb + 32768 + offB[n] + (kadd)); }
#define DO_MFMA(mb) { \
    __builtin_amdgcn_s_setprio(1); \
    _Pragma("unroll") \
    for (int m = 0; m < 4; m++) \
        _Pragma("unroll") \
        for (int n = 0; n < 4; n++) \
            acc[(mb) + m][n] = __builtin_amdgcn_mfma_f32_16x16x32_bf16( \
                af[m], bf[n], acc[(mb) + m][n], 0, 0, 0); \
    __builtin_amdgcn_s_setprio(0); }
#define ENTER_PHASE() { __builtin_amdgcn_s_barrier(); \
    asm volatile("s_waitcnt lgkmcnt(0)" ::: "memory"); \
    __builtin_amdgcn_sched_barrier(0); }

    // prologue: stage tile 0 (A-k0, B-k0, A-k1, B-k1), retire the k0 halves
    STAGE_A(0, 0);
    STAGE_B(32768, 0);
    STAGE_A(16384, 32);
    STAGE_B(49152, 32);
    asm volatile("s_waitcnt vmcnt(4)" ::: "memory");
    __builtin_amdgcn_s_barrier();

    for (int t = 0; t < NT; ++t) {
        int lb = (t & 1) << 16;
        int pb = lb ^ 65536;
        bool pf = (t + 1 < NT);
        unsigned eo = (unsigned)(t + 1) * 64;
        bf16x8s af[4], bf[4];

        // phase 0: k0, m0-3 x n0-3
        LDA_FRAGS(0, 0); LDB_FRAGS(0);
        if (pf) STAGE_A(pb, eo);
        ENTER_PHASE();
        DO_MFMA(0);
        __builtin_amdgcn_s_barrier();

        // phase 1: k0, m4-7 x n0-3
        LDA_FRAGS(4, 0);
        if (pf) STAGE_B(pb + 32768, eo);
        ENTER_PHASE();
        DO_MFMA(4);
        if (pf) asm volatile("s_waitcnt vmcnt(4)" ::: "memory");
        else    asm volatile("s_waitcnt vmcnt(0)" ::: "memory");
        __builtin_amdgcn_s_barrier();

        // phase 2: k1, m0-3 x n0-3
        LDA_FRAGS(0, 16384); LDB_FRAGS(16384);
        if (pf) STAGE_A(pb + 16384, eo + 32);
        ENTER_PHASE();
        DO_MFMA(0);
        __builtin_amdgcn_s_barrier();

        // phase 3: k1, m4-7 x n0-3
        LDA_FRAGS(4, 16384);
        if (pf) STAGE_B(pb + 49152, eo + 32);
        ENTER_PHASE();
        DO_MFMA(4);
        if (pf) asm volatile("s_waitcnt vmcnt(4)" ::: "memory");
        __builtin_amdgcn_s_barrier();
    }
#undef STAGE_A
#undef STAGE_B
#undef LDA_FRAGS
#undef LDB_FRAGS
#undef DO_MFMA
#undef ENTER_PHASE

    // epilogue: C/D map col = lane&15, row = (lane>>4)*4 + reg
    int rr = lj * 4;
#pragma unroll
    for (int m = 0; m < 8; m++) {
#pragma unroll
        for (int n = 0; n < 4; n++) {
            int gr = m0 + wm + m * 16 + rr;
            int gc = n0 + wn + n * 16 + lr;
            float bv = BIAS ? bias[gc] : 0.f;
#pragma unroll
            for (int r = 0; r < 4; r++) {
                float v = acc[m][n][r] + bv;
                size_t off = Coff + (size_t)(gr + r) * ldc + gc;
                if (OBF16) ((ushort*)Cv)[off] = f2bf(v);
                else       ((float*)Cv)[off]  = v;
            }
        }
    }
}

// ---------------------------------------------------------------------------
// Old 128x128 NT GEMM (m97 structure) - kept for the tiny NT step (K=128).
// ---------------------------------------------------------------------------
template<bool BIAS, bool OBF16, int BN>
__global__ __launch_bounds__(256)
void gemm_nt(const ushort* __restrict__ A, const ushort* __restrict__ B,
             const float* __restrict__ bias, void* __restrict__ Cv,
             int K, int lda, int ldb, int ldc, int ZH,
             long sAb, long sAh, long sBb, long sBh, long sCb, long sCh)
{
    __shared__ ushort As[128 * 32];
    __shared__ ushort Bs[BN * 32];

    int z  = blockIdx.z;
    int zb = z / ZH, zh = z - zb * ZH;
    const ushort* Ab = A + (size_t)(sAb * zb + sAh * zh);
    const ushort* Bb = B + (size_t)(sBb * zb + sBh * zh);
    size_t Coff = (size_t)(sCb * zb + sCh * zh);

    int m0 = blockIdx.x * 128, n0 = blockIdx.y * BN;
    int t = threadIdx.x;
    int l = t & 63, w = t >> 6;
    int wm, wn;
    if (BN == 128) { wm = (w >> 1) * 64; wn = (w & 1) * 64; }
    else           { wm = w * 32;        wn = 0; }
    constexpr int FM = (BN == 128) ? 4 : 2;
    constexpr int FN = 4;
    int lr = l & 15, lk = (l >> 4) * 8;

    f32x4 acc[FM][FN];
#pragma unroll
    for (int i = 0; i < FM; i++)
#pragma unroll
        for (int j = 0; j < FN; j++)
            acc[i][j] = (f32x4){0.f, 0.f, 0.f, 0.f};

    int c0 = t, c1 = t + 256;
    int r0 = c0 >> 2, k0c = (c0 & 3) * 8;
    int r1 = c1 >> 2, k1c = (c1 & 3) * 8;

    for (int kt = 0; kt < K; kt += 32) {
        __syncthreads();
        gload_lds16(Ab + (size_t)(m0 + r0) * lda + kt + k0c, &As[c0 * 8]);
        gload_lds16(Ab + (size_t)(m0 + r1) * lda + kt + k1c, &As[c1 * 8]);
        gload_lds16(Bb + (size_t)(n0 + r0) * ldb + kt + k0c, &Bs[c0 * 8]);
        if (BN == 128)
            gload_lds16(Bb + (size_t)(n0 + r1) * ldb + kt + k1c, &Bs[c1 * 8]);
        __syncthreads();

        bf16x8s af[FM], bf[FN];
#pragma unroll
        for (int i = 0; i < FM; i++)
            af[i] = *(const bf16x8s*)&As[(wm + i * 16 + lr) * 32 + lk];
#pragma unroll
        for (int i = 0; i < FN; i++)
            bf[i] = *(const bf16x8s*)&Bs[(wn + i * 16 + lr) * 32 + lk];
#pragma unroll
        for (int mi = 0; mi < FM; mi++)
#pragma unroll
            for (int ni = 0; ni < FN; ni++)
                acc[mi][ni] = __builtin_amdgcn_mfma_f32_16x16x32_bf16(
                    af[mi], bf[ni], acc[mi][ni], 0, 0, 0);
    }

    int rr = (l >> 4) * 4;
#pragma unroll
    for (int mi = 0; mi < FM; mi++) {
#pragma unroll
        for (int ni = 0; ni < FN; ni++) {
            int gr = m0 + wm + mi * 16 + rr;
            int gc = n0 + wn + ni * 16 + lr;
            float bv = BIAS ? bias[gc] : 0.f;
#pragma unroll
            for (int r = 0; r < 4; r++) {
                float v = acc[mi][ni][r] + bv;
                size_t off = Coff + (size_t)(gr + r) * ldc + gc;
                if (OBF16) ((ushort*)Cv)[off] = f2bf(v);
                else       ((float*)Cv)[off]  = v;
            }
        }
    }
}

// ---------------------------------------------------------------------------
// RoPE on bf16 QKV buffer [4096][6144] (Q cols 0-2047, K 2048-4095).
// Q -> compact QB [4096][2048]; K in place.
// ---------------------------------------------------------------------------
__global__ __launch_bounds__(256)
void rope_qk(ushort* __restrict__ QKV, const int* __restrict__ pos,
             ushort* __restrict__ QB)
{
    int tid = blockIdx.x * 256 + threadIdx.x;   // 4096*16*8 = 524288
    int row = tid >> 7;
    int r = tid & 127;
    int h = r >> 3, j = r & 7;
    int d0 = j * 8;
    float p = (float)pos[row];
    size_t qb = (size_t)row * 6144 + h * 128 + d0;

    bf16x8s q1 = *(const bf16x8s*)&QKV[qb];
    bf16x8s q2 = *(const bf16x8s*)&QKV[qb + 64];
    bf16x8s k1 = *(const bf16x8s*)&QKV[qb + 2048];
    bf16x8s k2 = *(const bf16x8s*)&QKV[qb + 2048 + 64];
    bf16x8s oq1, oq2, ok1, ok2;
#pragma unroll
    for (int i = 0; i < 8; i++) {
        float d = (float)(d0 + i);
        float ang = p * exp2f(d * (-13.287712379549449f / 64.0f));
        float s, c;
        sincosf(ang, &s, &c);
        float a = b2f((ushort)q1[i]), b = b2f((ushort)q2[i]);
        oq1[i] = (short)f2bf(a * c - b * s);
        oq2[i] = (short)f2bf(b * c + a * s);
        float e = b2f((ushort)k1[i]), f = b2f((ushort)k2[i]);
        ok1[i] = (short)f2bf(e * c - f * s);
        ok2[i] = (short)f2bf(f * c + e * s);
    }
    size_t ob = (size_t)row * 2048 + h * 128 + d0;
    *(bf16x8s*)&QB[ob]      = oq1;
    *(bf16x8s*)&QB[ob + 64] = oq2;
    *(bf16x8s*)&QKV[qb + 2048]      = ok1;
    *(bf16x8s*)&QKV[qb + 2048 + 64] = ok2;
}

// ---------------------------------------------------------------------------
// K^T V partials from bf16 QKV buf. grid (32 bh, 16 s-slices).
// part[(slice*32 + bh)*16384 + d1*128 + d2]  (fp32, lives in d_out)
// ---------------------------------------------------------------------------
__global__ __launch_bounds__(256)
void ktv_partial(const ushort* __restrict__ QKV, float* __restrict__ part)
{
    int bh = blockIdx.x;
    int b = bh >> 4, h = bh & 15;
    int s0 = blockIdx.y * 128;
    const ushort* Kp = QKV + (size_t)(b * 2048 + s0) * 6144 + 2048 + h * 128;
    const ushort* Vp = Kp + 2048;

    __shared__ ushort Ks[32][128];
    __shared__ ushort Vs[32][128];

    int t = threadIdx.x;
    int tx = t & 15, ty = t >> 4;
    float acc[8][8];
#pragma unroll
    for (int i = 0; i < 8; i++)
#pragma unroll
        for (int j = 0; j < 8; j++) acc[i][j] = 0.f;

    for (int sb = 0; sb < 128; sb += 32) {
        __syncthreads();
#pragma unroll
        for (int i = 0; i < 2; i++) {
            int idx = t + i * 256;
            int rw = idx >> 4, c8 = (idx & 15) * 8;
            *(bf16x8s*)&Ks[rw][c8] = *(const bf16x8s*)&Kp[(size_t)(sb + rw) * 6144 + c8];
            *(bf16x8s*)&Vs[rw][c8] = *(const bf16x8s*)&Vp[(size_t)(sb + rw) * 6144 + c8];
        }
        __syncthreads();
        for (int ss = 0; ss < 32; ss++) {
            bf16x8s kvv = *(const bf16x8s*)&Ks[ss][tx * 8];
            bf16x8s vvv = *(const bf16x8s*)&Vs[ss][ty * 8];
            float kv[8], vv[8];
#pragma unroll
            for (int i = 0; i < 8; i++) { kv[i] = b2f((ushort)kvv[i]); vv[i] = b2f((ushort)vvv[i]); }
#pragma unroll
            for (int i = 0; i < 8; i++)
#pragma unroll
                for (int j = 0; j < 8; j++)
                    acc[i][j] += kv[i] * vv[j];
        }
    }
    float* pp = part + ((size_t)blockIdx.y * 32 + bh) * 16384;
#pragma unroll
    for (int i = 0; i < 8; i++)
#pragma unroll
        for (int j = 0; j < 8; j++)
            pp[(tx * 8 + i) * 128 + (ty * 8 + j)] = acc[i][j];
}

// Reduce 16 partials -> Mb (bf16), scaled by 1/sqrt(128).
__global__ __launch_bounds__(256)
void reduce_ktv(const float* __restrict__ part, ushort* __restrict__ Mb)
{
    int i = blockIdx.x * 256 + threadIdx.x;   // 32*16384 = 524288
    float s = 0.f;
#pragma unroll
    for (int p = 0; p < 16; p++) s += part[(size_t)p * 524288 + i];
    Mb[i] = f2bf(s * 0.08838834764831845f);
}

// fp32 -> bf16 convert, float4-vectorized (hidden states).
__global__ __launch_bounds__(256)
void conv_f32_bf16(const float* __restrict__ in, ushort* __restrict__ out, int n4)
{
    int i = blockIdx.x * 256 + threadIdx.x;
    if (i >= n4) return;
    float4 v = ((const float4*)in)[i];
    ushort4 o;
    o.x = f2bf(v.x); o.y = f2bf(v.y); o.z = f2bf(v.z); o.w = f2bf(v.w);
    ((ushort4*)out)[i] = o;
}

// All four weights -> bf16 in one launch (Wq,Wk,Wv stacked, Wo separate).
__global__ __launch_bounds__(256)
void conv_weights(const float* __restrict__ w0, const float* __restrict__ w1,
                  const float* __restrict__ w2, const float* __restrict__ w3,
                  ushort* __restrict__ qkv, ushort* __restrict__ wo)
{
    int i = blockIdx.x * 256 + threadIdx.x;
    int id = i >> 20;
    int off = i & 1048575;
    const float* src = (id == 0) ? w0 : (id == 1) ? w1 : (id == 2) ? w2 : w3;
    float4 v = ((const float4*)src)[off];
    ushort4 o;
    o.x = f2bf(v.x); o.y = f2bf(v.y); o.z = f2bf(v.z); o.w = f2bf(v.w);
    if (id < 3) ((ushort4*)qkv)[(size_t)id * 1048576 + off] = o;
    else        ((ushort4*)wo)[off] = o;
}

// Stack bq,bk,bv -> 6144-float buffer.
__global__ __launch_bounds__(256)
void pack_bias(const float* __restrict__ bq, const float* __restrict__ bk,
               const float* __restrict__ bv, float* __restrict__ bqkv)
{
    int i = blockIdx.x * 256 + threadIdx.x;
    float v = (i < 2048) ? bq[i] : (i < 4096) ? bk[i - 2048] : bv[i - 4096];
    bqkv[i] = v;
}

// ---------------------------------------------------------------------------
// Workspace (~102 MB): same layout as rounds 3-4.
//   HSB/QB @ 0        : 16,777,216   WQKV/NT @ 16777216 : 25,165,824
//   WOB @ 41943040 : 8,388,608       BQKV @ 50331648 : 24,576
//   QKVB @ 50356224 : 50,331,648     MB @ 100687872 : 1,048,576
// d_out doubles as ktv-partial scratch; final GEMM writes it last.
// ---------------------------------------------------------------------------
extern "C" void kernel_launch(void* const* d_in, const int* in_sizes, int n_in,
                              void* d_out, int out_size, void* d_ws, size_t ws_size,
                              hipStream_t stream)
{
    const float* hs = (const float*)d_in[0];
    const int*  pos = (const int*)d_in[1];
    const float* Wq = (const float*)d_in[2];
    const float* bq = (const float*)d_in[3];
    const float* Wk = (const float*)d_in[4];
    const float* bk = (const float*)d_in[5];
    const float* Wv = (const float*)d_in[6];
    const float* bv = (const float*)d_in[7];
    const float* Wo = (const float*)d_in[8];
    float* out = (float*)d_out;
    char* ws = (char*)d_ws;

    ushort* HSB  = (ushort*)(ws + 0);
    ushort* QB   = (ushort*)(ws + 0);           // HSB dead after QKV GEMM
    ushort* WQKV = (ushort*)(ws + 16777216);
    ushort* NT   = (ushort*)(ws + 16777216);    // WQKV dead after QKV GEMM
    ushort* WOB  = (ushort*)(ws + 41943040);
    float*  BQKV = (float*)(ws + 50331648);
    ushort* QKVB = (ushort*)(ws + 50356224);
    ushort* MB   = (ushort*)(ws + 100687872);
    float*  PART = out;                          // d_out as scratch until final

    dim3 blk(256);

    conv_f32_bf16<<<8192, blk, 0, stream>>>(hs, HSB, 2097152);
    conv_weights<<<16384, blk, 0, stream>>>(Wq, Wk, Wv, Wo, WQKV, WOB);
    pack_bias<<<24, blk, 0, stream>>>(bq, bk, bv, BQKV);

    // Fused QKV: [4096x2048] @ [6144x2048]^T -> QKVB [4096][6144] bf16
    gemm256<true, true><<<dim3(16, 24, 1), dim3(512), 0, stream>>>(
        HSB, WQKV, BQKV, QKVB, 2048, 2048, 2048, 6144, 0, 0, 0);

    rope_qk<<<2048, blk, 0, stream>>>(QKVB, pos, QB);

    ktv_partial<<<dim3(32, 16, 1), blk, 0, stream>>>(QKVB, PART);
    reduce_ktv<<<2048, blk, 0, stream>>>(PART, MB);

    // NT_b[j][h*128+d1] = sum_d2 Wo_b16[j][h*128+d2] * M_bh[d1][d2]
    gemm_nt<false, true, 128><<<dim3(16, 1, 32), blk, 0, stream>>>(
        WOB, MB, nullptr, NT, 128, 2048, 128, 2048, 16,
        0, 128, 262144, 16384, 4194304, 128);

    // out[b] = QB_b @ NT_b^T
    gemm256<false, false><<<dim3(8, 8, 2), dim3(512), 0, stream>>>(
        QB, NT, nullptr, out, 2048, 2048, 2048, 2048,
        4194304, 4194304, 4194304);
}

// Round 6
// 382.051 us; speedup vs baseline: 1.0294x; 1.0294x over previous
//
#include <hip/hip_runtime.h>
#include <hip/hip_bf16.h>

// DreamAttention on MI355X.
// Math: out = (Q K^T/sqrt(HD)) V Wo^T  (reference discards softmax!)
//     = Q @ NT_b^T  where NT_b[j][h*128+d1] = sum_d2 (K^T V/sqrt(HD))_bh[d1][d2] * Wo[j][h*128+d2]
// B=2, S=2048, D=2048, NH=16, HD=128.
// Round 6: AITER-style minimal-barrier K-loop: 2 barriers per BK=64 K-tile
// (32 MFMA/barrier), counted lgkmcnt(4)/vmcnt(4), no pre-MFMA lockstep
// barrier -> waves drift, reads hide under other waves' MFMA, setprio pays.

typedef __attribute__((ext_vector_type(8))) short bf16x8s;   // 8 bf16 in 4 VGPRs
typedef __attribute__((ext_vector_type(4))) float f32x4;

__device__ __forceinline__ ushort f2bf(float f) {
    union { float f; unsigned int u; } x; x.f = f;
    unsigned int u = x.u;
    unsigned int r = (u + 0x7fffu + ((u >> 16) & 1u)) >> 16;   // RTN
    return (ushort)r;
}
__device__ __forceinline__ float b2f(ushort u) {
    union { unsigned int u; float f; } x; x.u = ((unsigned int)u) << 16;
    return x.f;
}

__device__ __forceinline__ void gload_lds16(const void* g, void* l) {
    __builtin_amdgcn_global_load_lds((__attribute__((address_space(1))) const void*)g,
                                     (__attribute__((address_space(3))) void*)l, 16, 0, 0);
}

// ---------------------------------------------------------------------------
// 256x256 NT GEMM, BK=64, 512 thr (8 waves 2Mx4N), minimal-barrier schedule.
// C[m][n] = sum_k A[m][k]*B[n][k] (+bias[n]); bf16 in, fp32 acc.
//
// LDS 128KB: buf b (b=tile&1) at b*65536; A k0 at +0, A k1 at +16384,
// B k0 at +32768, B k1 at +49152. Each 16KB block = 256 rows x 32 cols bf16,
// round-4 proven zero-conflict layout: pr=r>>1 (128B rows), chunk pos =
// (((r&1)<<2)|j) ^ (pr&7). Staging dst lane-linear, src inverse-permuted.
//
// Stage units per tile t (for t+1, into buf^1): U0=A-k0, U1=B-k0, U2=A-k1,
// U3=B-k1 (2 gloads each), issued in that order. vmcnt ledger (steady state,
// entering tile with {U2',U3'}=4 in flight):
//   H0: reads k0 (12) | U0 | lgk(4) | 16 MFMA | lgk(0) | 16 MFMA | U1 |
//       vmcnt(4) retires U2',U3' (age ~1 tile >> HBM 900cy) | BAR
//   H1: reads k1 (12) | U2 | lgk(4) | 16 MFMA | lgk(0) | 16 MFMA | U3 |
//       vmcnt(4) retires U0,U1 | BAR
// 2 barriers/K-tile = 32 MFMA per barrier (AITER ratio). WAR on buf^1 safe:
// old content's reads finished before the previous tile-end barrier.
// ---------------------------------------------------------------------------
template<bool BIAS, bool OBF16>
__global__ __launch_bounds__(512, 2)
void gemm256(const ushort* __restrict__ A, const ushort* __restrict__ B,
             const float* __restrict__ bias, void* __restrict__ Cv,
             int K, int lda, int ldb, int ldc,
             long sAb, long sBb, long sCb)
{
    __shared__ char smem[131072];

    int z = blockIdx.z;
    const ushort* Ab = A + (size_t)sAb * z;
    const ushort* Bb = B + (size_t)sBb * z;
    size_t Coff = (size_t)sCb * z;

    // XCD-aware bijective workgroup swizzle (nwg % 8 == 0 for all our grids)
    int nwgx = gridDim.x;
    int nwg = nwgx * gridDim.y;
    int wg = blockIdx.y * nwgx + blockIdx.x;
    int swz = ((nwg & 7) == 0) ? (wg & 7) * (nwg >> 3) + (wg >> 3) : wg;
    int m0 = (swz % nwgx) * 256;
    int n0 = (swz / nwgx) * 256;

    int tid = threadIdx.x;
    int l = tid & 63, wid = tid >> 6;
    int wm = (wid >> 2) * 128;     // wave row half: 0 or 128
    int wn = (wid & 3) * 64;       // wave col quarter: 0/64/128/192
    int lr = l & 15, lj = l >> 4;  // frag: row-within-16, 16B k-chunk

    // fragment LDS byte offsets within a 16KB block
    int offA[8], offB[4];
#pragma unroll
    for (int m = 0; m < 8; m++) {
        int r = wm + m * 16 + lr;
        offA[m] = (r >> 1) * 128 + (((((r & 1) << 2) | lj) ^ ((r >> 1) & 7)) << 4);
    }
#pragma unroll
    for (int n = 0; n < 4; n++) {
        int r = wn + n * 16 + lr;
        offB[n] = (r >> 1) * 128 + (((((r & 1) << 2) | lj) ^ ((r >> 1) & 7)) << 4);
    }

    // staging: 2 chunks/thread per 16KB unit; dst lane-linear, src from the
    // inverse swizzle map (round-4 proven, measured 0 bank conflicts).
    unsigned srcA0, srcA1, srcB0, srcB1;
    int dst0 = tid * 16, dst1 = dst0 + 8192;
    {
        int c0 = tid, c1 = tid + 512;
        int pr0 = c0 >> 3, up0 = (c0 & 7) ^ (pr0 & 7);
        int r0 = (pr0 << 1) | (up0 >> 2), j0 = up0 & 3;
        int pr1 = c1 >> 3, up1 = (c1 & 7) ^ (pr1 & 7);
        int r1 = (pr1 << 1) | (up1 >> 2), j1 = up1 & 3;
        srcA0 = (unsigned)(m0 + r0) * lda + j0 * 8;
        srcA1 = (unsigned)(m0 + r1) * lda + j1 * 8;
        srcB0 = (unsigned)(n0 + r0) * ldb + j0 * 8;
        srcB1 = (unsigned)(n0 + r1) * ldb + j1 * 8;
    }

    f32x4 acc[8][4];
#pragma unroll
    for (int m = 0; m < 8; m++)
#pragma unroll
        for (int n = 0; n < 4; n++)
            acc[m][n] = (f32x4){0.f, 0.f, 0.f, 0.f};

    int NT = K >> 6;   // K-tiles of 64 (K % 64 == 0, NT >= 2)

#define STAGE_A(ldsbyte, eoff) { \
    gload_lds16(Ab + srcA0 + (eoff), smem + (ldsbyte) + dst0); \
    gload_lds16(Ab + srcA1 + (eoff), smem + (ldsbyte) + dst1); }
#define STAGE_B(ldsbyte, eoff) { \
    gload_lds16(Bb + srcB0 + (eoff), smem + (ldsbyte) + dst0); \
    gload_lds16(Bb + srcB1 + (eoff), smem + (ldsbyte) + dst1); }
#define MFMA_HALF(mb) { \
    __builtin_amdgcn_s_setprio(1); \
    _Pragma("unroll") \
    for (int m = 0; m < 4; m++) \
        _Pragma("unroll") \
        for (int n = 0; n < 4; n++) \
            acc[(mb) + m][n] = __builtin_amdgcn_mfma_f32_16x16x32_bf16( \
                af[(mb) + m], bf[n], acc[(mb) + m][n], 0, 0, 0); \
    __builtin_amdgcn_s_setprio(0); }

    // prologue: stage tile 0 into buf0 (U0,U1,U2,U3), retire U0,U1
    STAGE_A(0, 0);
    STAGE_B(32768, 0);
    STAGE_A(16384, 32);
    STAGE_B(49152, 32);
    asm volatile("s_waitcnt vmcnt(4)" ::: "memory");
    __builtin_amdgcn_s_barrier();

    for (int t = 0; t < NT; ++t) {
        int lb = (t & 1) << 16;
        int pb = lb ^ 65536;
        bool pf = (t + 1 < NT);
        unsigned eo = (unsigned)(t + 1) * 64;
        bf16x8s af[8], bf[4];

        // ================= K-half 0 =================
#pragma unroll
        for (int m = 0; m < 4; m++)
            af[m] = *(const bf16x8s*)(smem + lb + offA[m]);
#pragma unroll
        for (int n = 0; n < 4; n++)
            bf[n] = *(const bf16x8s*)(smem + lb + 32768 + offB[n]);
        if (pf) STAGE_A(pb, eo);                       // U0
#pragma unroll
        for (int m = 4; m < 8; m++)
            af[m] = *(const bf16x8s*)(smem + lb + offA[m]);
        asm volatile("s_waitcnt lgkmcnt(4)" ::: "memory");   // first 8 reads done
        __builtin_amdgcn_sched_barrier(0);
        MFMA_HALF(0);
        asm volatile("s_waitcnt lgkmcnt(0)" ::: "memory");
        __builtin_amdgcn_sched_barrier(0);
        MFMA_HALF(4);
        if (pf) STAGE_B(pb + 32768, eo);               // U1
        if (pf) asm volatile("s_waitcnt vmcnt(4)" ::: "memory");   // U2',U3' landed
        else    asm volatile("s_waitcnt vmcnt(0)" ::: "memory");
        __builtin_amdgcn_s_barrier();

        // ================= K-half 1 =================
#pragma unroll
        for (int m = 0; m < 4; m++)
            af[m] = *(const bf16x8s*)(smem + lb + 16384 + offA[m]);
#pragma unroll
        for (int n = 0; n < 4; n++)
            bf[n] = *(const bf16x8s*)(smem + lb + 49152 + offB[n]);
        if (pf) STAGE_A(pb + 16384, eo + 32);          // U2
#pragma unroll
        for (int m = 4; m < 8; m++)
            af[m] = *(const bf16x8s*)(smem + lb + 16384 + offA[m]);
        asm volatile("s_waitcnt lgkmcnt(4)" ::: "memory");
        __builtin_amdgcn_sched_barrier(0);
        MFMA_HALF(0);
        asm volatile("s_waitcnt lgkmcnt(0)" ::: "memory");
        __builtin_amdgcn_sched_barrier(0);
        MFMA_HALF(4);
        if (pf) {
            STAGE_B(pb + 49152, eo + 32);              // U3
            asm volatile("s_waitcnt vmcnt(4)" ::: "memory");       // U0,U1 landed
            __builtin_amdgcn_s_barrier();
        }
    }
#undef STAGE_A
#undef STAGE_B
#undef MFMA_HALF

    // epilogue: C/D map col = lane&15, row = (lane>>4)*4 + reg
    int rr = lj * 4;
#pragma unroll
    for (int m = 0; m < 8; m++) {
#pragma unroll
        for (int n = 0; n < 4; n++) {
            int gr = m0 + wm + m * 16 + rr;
            int gc = n0 + wn + n * 16 + lr;
            float bv = BIAS ? bias[gc] : 0.f;
#pragma unroll
            for (int r = 0; r < 4; r++) {
                float v = acc[m][n][r] + bv;
                size_t off = Coff + (size_t)(gr + r) * ldc + gc;
                if (OBF16) ((ushort*)Cv)[off] = f2bf(v);
                else       ((float*)Cv)[off]  = v;
            }
        }
    }
}

// ---------------------------------------------------------------------------
// Old 128x128 NT GEMM (m97 structure) - kept for the tiny NT step (K=128).
// ---------------------------------------------------------------------------
template<bool BIAS, bool OBF16, int BN>
__global__ __launch_bounds__(256)
void gemm_nt(const ushort* __restrict__ A, const ushort* __restrict__ B,
             const float* __restrict__ bias, void* __restrict__ Cv,
             int K, int lda, int ldb, int ldc, int ZH,
             long sAb, long sAh, long sBb, long sBh, long sCb, long sCh)
{
    __shared__ ushort As[128 * 32];
    __shared__ ushort Bs[BN * 32];

    int z  = blockIdx.z;
    int zb = z / ZH, zh = z - zb * ZH;
    const ushort* Ab = A + (size_t)(sAb * zb + sAh * zh);
    const ushort* Bb = B + (size_t)(sBb * zb + sBh * zh);
    size_t Coff = (size_t)(sCb * zb + sCh * zh);

    int m0 = blockIdx.x * 128, n0 = blockIdx.y * BN;
    int t = threadIdx.x;
    int l = t & 63, w = t >> 6;
    int wm, wn;
    if (BN == 128) { wm = (w >> 1) * 64; wn = (w & 1) * 64; }
    else           { wm = w * 32;        wn = 0; }
    constexpr int FM = (BN == 128) ? 4 : 2;
    constexpr int FN = 4;
    int lr = l & 15, lk = (l >> 4) * 8;

    f32x4 acc[FM][FN];
#pragma unroll
    for (int i = 0; i < FM; i++)
#pragma unroll
        for (int j = 0; j < FN; j++)
            acc[i][j] = (f32x4){0.f, 0.f, 0.f, 0.f};

    int c0 = t, c1 = t + 256;
    int r0 = c0 >> 2, k0c = (c0 & 3) * 8;
    int r1 = c1 >> 2, k1c = (c1 & 3) * 8;

    for (int kt = 0; kt < K; kt += 32) {
        __syncthreads();
        gload_lds16(Ab + (size_t)(m0 + r0) * lda + kt + k0c, &As[c0 * 8]);
        gload_lds16(Ab + (size_t)(m0 + r1) * lda + kt + k1c, &As[c1 * 8]);
        gload_lds16(Bb + (size_t)(n0 + r0) * ldb + kt + k0c, &Bs[c0 * 8]);
        if (BN == 128)
            gload_lds16(Bb + (size_t)(n0 + r1) * ldb + kt + k1c, &Bs[c1 * 8]);
        __syncthreads();

        bf16x8s af[FM], bf[FN];
#pragma unroll
        for (int i = 0; i < FM; i++)
            af[i] = *(const bf16x8s*)&As[(wm + i * 16 + lr) * 32 + lk];
#pragma unroll
        for (int i = 0; i < FN; i++)
            bf[i] = *(const bf16x8s*)&Bs[(wn + i * 16 + lr) * 32 + lk];
#pragma unroll
        for (int mi = 0; mi < FM; mi++)
#pragma unroll
            for (int ni = 0; ni < FN; ni++)
                acc[mi][ni] = __builtin_amdgcn_mfma_f32_16x16x32_bf16(
                    af[mi], bf[ni], acc[mi][ni], 0, 0, 0);
    }

    int rr = (l >> 4) * 4;
#pragma unroll
    for (int mi = 0; mi < FM; mi++) {
#pragma unroll
        for (int ni = 0; ni < FN; ni++) {
            int gr = m0 + wm + mi * 16 + rr;
            int gc = n0 + wn + ni * 16 + lr;
            float bv = BIAS ? bias[gc] : 0.f;
#pragma unroll
            for (int r = 0; r < 4; r++) {
                float v = acc[mi][ni][r] + bv;
                size_t off = Coff + (size_t)(gr + r) * ldc + gc;
                if (OBF16) ((ushort*)Cv)[off] = f2bf(v);
                else       ((float*)Cv)[off]  = v;
            }
        }
    }
}

// ---------------------------------------------------------------------------
// RoPE on bf16 QKV buffer [4096][6144] (Q cols 0-2047, K 2048-4095).
// Q -> compact QB [4096][2048]; K in place.
// ---------------------------------------------------------------------------
__global__ __launch_bounds__(256)
void rope_qk(ushort* __restrict__ QKV, const int* __restrict__ pos,
             ushort* __restrict__ QB)
{
    int tid = blockIdx.x * 256 + threadIdx.x;   // 4096*16*8 = 524288
    int row = tid >> 7;
    int r = tid & 127;
    int h = r >> 3, j = r & 7;
    int d0 = j * 8;
    float p = (float)pos[row];
    size_t qb = (size_t)row * 6144 + h * 128 + d0;

    bf16x8s q1 = *(const bf16x8s*)&QKV[qb];
    bf16x8s q2 = *(const bf16x8s*)&QKV[qb + 64];
    bf16x8s k1 = *(const bf16x8s*)&QKV[qb + 2048];
    bf16x8s k2 = *(const bf16x8s*)&QKV[qb + 2048 + 64];
    bf16x8s oq1, oq2, ok1, ok2;
#pragma unroll
    for (int i = 0; i < 8; i++) {
        float d = (float)(d0 + i);
        float ang = p * exp2f(d * (-13.287712379549449f / 64.0f));
        float s, c;
        sincosf(ang, &s, &c);
        float a = b2f((ushort)q1[i]), b = b2f((ushort)q2[i]);
        oq1[i] = (short)f2bf(a * c - b * s);
        oq2[i] = (short)f2bf(b * c + a * s);
        float e = b2f((ushort)k1[i]), f = b2f((ushort)k2[i]);
        ok1[i] = (short)f2bf(e * c - f * s);
        ok2[i] = (short)f2bf(f * c + e * s);
    }
    size_t ob = (size_t)row * 2048 + h * 128 + d0;
    *(bf16x8s*)&QB[ob]      = oq1;
    *(bf16x8s*)&QB[ob + 64] = oq2;
    *(bf16x8s*)&QKV[qb + 2048]      = ok1;
    *(bf16x8s*)&QKV[qb + 2048 + 64] = ok2;
}

// ---------------------------------------------------------------------------
// K^T V partials from bf16 QKV buf. grid (32 bh, 16 s-slices).
// part[(slice*32 + bh)*16384 + d1*128 + d2]  (fp32, lives in d_out)
// ---------------------------------------------------------------------------
__global__ __launch_bounds__(256)
void ktv_partial(const ushort* __restrict__ QKV, float* __restrict__ part)
{
    int bh = blockIdx.x;
    int b = bh >> 4, h = bh & 15;
    int s0 = blockIdx.y * 128;
    const ushort* Kp = QKV + (size_t)(b * 2048 + s0) * 6144 + 2048 + h * 128;
    const ushort* Vp = Kp + 2048;

    __shared__ ushort Ks[32][128];
    __shared__ ushort Vs[32][128];

    int t = threadIdx.x;
    int tx = t & 15, ty = t >> 4;
    float acc[8][8];
#pragma unroll
    for (int i = 0; i < 8; i++)
#pragma unroll
        for (int j = 0; j < 8; j++) acc[i][j] = 0.f;

    for (int sb = 0; sb < 128; sb += 32) {
        __syncthreads();
#pragma unroll
        for (int i = 0; i < 2; i++) {
            int idx = t + i * 256;
            int rw = idx >> 4, c8 = (idx & 15) * 8;
            *(bf16x8s*)&Ks[rw][c8] = *(const bf16x8s*)&Kp[(size_t)(sb + rw) * 6144 + c8];
            *(bf16x8s*)&Vs[rw][c8] = *(const bf16x8s*)&Vp[(size_t)(sb + rw) * 6144 + c8];
        }
        __syncthreads();
        for (int ss = 0; ss < 32; ss++) {
            bf16x8s kvv = *(const bf16x8s*)&Ks[ss][tx * 8];
            bf16x8s vvv = *(const bf16x8s*)&Vs[ss][ty * 8];
            float kv[8], vv[8];
#pragma unroll
            for (int i = 0; i < 8; i++) { kv[i] = b2f((ushort)kvv[i]); vv[i] = b2f((ushort)vvv[i]); }
#pragma unroll
            for (int i = 0; i < 8; i++)
#pragma unroll
                for (int j = 0; j < 8; j++)
                    acc[i][j] += kv[i] * vv[j];
        }
    }
    float* pp = part + ((size_t)blockIdx.y * 32 + bh) * 16384;
#pragma unroll
    for (int i = 0; i < 8; i++)
#pragma unroll
        for (int j = 0; j < 8; j++)
            pp[(tx * 8 + i) * 128 + (ty * 8 + j)] = acc[i][j];
}

// Reduce 16 partials -> Mb (bf16), scaled by 1/sqrt(128).
__global__ __launch_bounds__(256)
void reduce_ktv(const float* __restrict__ part, ushort* __restrict__ Mb)
{
    int i = blockIdx.x * 256 + threadIdx.x;   // 32*16384 = 524288
    float s = 0.f;
#pragma unroll
    for (int p = 0; p < 16; p++) s += part[(size_t)p * 524288 + i];
    Mb[i] = f2bf(s * 0.08838834764831845f);
}

// fp32 -> bf16 convert, float4-vectorized (hidden states).
__global__ __launch_bounds__(256)
void conv_f32_bf16(const float* __restrict__ in, ushort* __restrict__ out, int n4)
{
    int i = blockIdx.x * 256 + threadIdx.x;
    if (i >= n4) return;
    float4 v = ((const float4*)in)[i];
    ushort4 o;
    o.x = f2bf(v.x); o.y = f2bf(v.y); o.z = f2bf(v.z); o.w = f2bf(v.w);
    ((ushort4*)out)[i] = o;
}

// All four weights -> bf16 in one launch (Wq,Wk,Wv stacked, Wo separate).
__global__ __launch_bounds__(256)
void conv_weights(const float* __restrict__ w0, const float* __restrict__ w1,
                  const float* __restrict__ w2, const float* __restrict__ w3,
                  ushort* __restrict__ qkv, ushort* __restrict__ wo)
{
    int i = blockIdx.x * 256 + threadIdx.x;
    int id = i >> 20;
    int off = i & 1048575;
    const float* src = (id == 0) ? w0 : (id == 1) ? w1 : (id == 2) ? w2 : w3;
    float4 v = ((const float4*)src)[off];
    ushort4 o;
    o.x = f2bf(v.x); o.y = f2bf(v.y); o.z = f2bf(v.z); o.w = f2bf(v.w);
    if (id < 3) ((ushort4*)qkv)[(size_t)id * 1048576 + off] = o;
    else        ((ushort4*)wo)[off] = o;
}

// Stack bq,bk,bv -> 6144-float buffer.
__global__ __launch_bounds__(256)
void pack_bias(const float* __restrict__ bq, const float* __restrict__ bk,
               const float* __restrict__ bv, float* __restrict__ bqkv)
{
    int i = blockIdx.x * 256 + threadIdx.x;
    float v = (i < 2048) ? bq[i] : (i < 4096) ? bk[i - 2048] : bv[i - 4096];
    bqkv[i] = v;
}

// ---------------------------------------------------------------------------
// Workspace (~102 MB): same layout as rounds 3-5.
//   HSB/QB @ 0        : 16,777,216   WQKV/NT @ 16777216 : 25,165,824
//   WOB @ 41943040 : 8,388,608       BQKV @ 50331648 : 24,576
//   QKVB @ 50356224 : 50,331,648     MB @ 100687872 : 1,048,576
// d_out doubles as ktv-partial scratch; final GEMM writes it last.
// ---------------------------------------------------------------------------
extern "C" void kernel_launch(void* const* d_in, const int* in_sizes, int n_in,
                              void* d_out, int out_size, void* d_ws, size_t ws_size,
                              hipStream_t stream)
{
    const float* hs = (const float*)d_in[0];
    const int*  pos = (const int*)d_in[1];
    const float* Wq = (const float*)d_in[2];
    const float* bq = (const float*)d_in[3];
    const float* Wk = (const float*)d_in[4];
    const float* bk = (const float*)d_in[5];
    const float* Wv = (const float*)d_in[6];
    const float* bv = (const float*)d_in[7];
    const float* Wo = (const float*)d_in[8];
    float* out = (float*)d_out;
    char* ws = (char*)d_ws;

    ushort* HSB  = (ushort*)(ws + 0);
    ushort* QB   = (ushort*)(ws + 0);           // HSB dead after QKV GEMM
    ushort* WQKV = (ushort*)(ws + 16777216);
    ushort* NT   = (ushort*)(ws + 16777216);    // WQKV dead after QKV GEMM
    ushort* WOB  = (ushort*)(ws + 41943040);
    float*  BQKV = (float*)(ws + 50331648);
    ushort* QKVB = (ushort*)(ws + 50356224);
    ushort* MB   = (ushort*)(ws + 100687872);
    float*  PART = out;                          // d_out as scratch until final

    dim3 blk(256);

    conv_f32_bf16<<<8192, blk, 0, stream>>>(hs, HSB, 2097152);
    conv_weights<<<16384, blk, 0, stream>>>(Wq, Wk, Wv, Wo, WQKV, WOB);
    pack_bias<<<24, blk, 0, stream>>>(bq, bk, bv, BQKV);

    // Fused QKV: [4096x2048] @ [6144x2048]^T -> QKVB [4096][6144] bf16
    gemm256<true, true><<<dim3(16, 24, 1), dim3(512), 0, stream>>>(
        HSB, WQKV, BQKV, QKVB, 2048, 2048, 2048, 6144, 0, 0, 0);

    rope_qk<<<2048, blk, 0, stream>>>(QKVB, pos, QB);

    ktv_partial<<<dim3(32, 16, 1), blk, 0, stream>>>(QKVB, PART);
    reduce_ktv<<<2048, blk, 0, stream>>>(PART, MB);

    // NT_b[j][h*128+d1] = sum_d2 Wo_b16[j][h*128+d2] * M_bh[d1][d2]
    gemm_nt<false, true, 128><<<dim3(16, 1, 32), blk, 0, stream>>>(
        WOB, MB, nullptr, NT, 128, 2048, 128, 2048, 16,
        0, 128, 262144, 16384, 4194304, 128);

    // out[b] = QB_b @ NT_b^T
    gemm256<false, false><<<dim3(8, 8, 2), dim3(512), 0, stream>>>(
        QB, NT, nullptr, out, 2048, 2048, 2048, 2048,
        4194304, 4194304, 4194304);
}